// Round 4
// baseline (5937.400 us; speedup 1.0000x reference)
//
#include <hip/hip_runtime.h>
#include <hip/hip_cooperative_groups.h>
#include <math.h>

namespace cg = cooperative_groups;

typedef __attribute__((ext_vector_type(8))) short bf16x8;
typedef __attribute__((ext_vector_type(8))) unsigned short u16x8;
typedef __attribute__((ext_vector_type(4))) float f32x4;

#define NB 64
#define NP 196
#define ND 2048
#define NA 512
#define NH 512
#define NE 512
#define NV 10000
#define NT 19
#define NKX 3072
#define NROW (NB*NP)
#define NVP 10112          // padded vocab (79*128)
#define MROW 1280          // padded hsb rows (10*128)
#define PP 200             // padded p-dim for ftr

__device__ __forceinline__ unsigned short f2bu(float f){
    unsigned int u; __builtin_memcpy(&u, &f, 4);
    u = (u + 0x7FFFu + ((u >> 16) & 1u)) >> 16;
    return (unsigned short)u;
}
__device__ __forceinline__ float b2f(short s){
    unsigned int u = ((unsigned int)(unsigned short)s) << 16;
    float f; __builtin_memcpy(&f, &u, 4); return f;
}
__device__ __forceinline__ float sigm(float x){ return 1.f/(1.f + __expf(-x)); }

__device__ __forceinline__ void gll16(const void* g, void* l){
    __builtin_amdgcn_global_load_lds(
        (const __attribute__((address_space(1))) void*)g,
        (__attribute__((address_space(3))) void*)l, 16, 0, 0);
}

// ---------------- setup kernels ----------------

__global__ void k_cast4(const float4* __restrict__ src, ushort4* __restrict__ dst, int n4){
    int stride = gridDim.x * blockDim.x;
    for (int i = blockIdx.x*blockDim.x + threadIdx.x; i < n4; i += stride){
        float4 v = src[i];
        ushort4 o = { f2bu(v.x), f2bu(v.y), f2bu(v.z), f2bu(v.w) };
        dst[i] = o;
    }
}

// wcat[j][0:2560]=W_ih[j], [2560:3072]=W_hh[j]  (float4 loads)
__global__ void k_wcat4(const float4* __restrict__ wih, const float4* __restrict__ whh,
                        ushort4* __restrict__ wcat){
    int j = blockIdx.x;                       // 0..2047
    int k4 = blockIdx.y*256 + threadIdx.x;    // 0..767
    if (k4 >= 768) return;
    float4 v = (k4 < 640) ? wih[(size_t)j*640 + k4] : whh[(size_t)j*128 + (k4 - 640)];
    ushort4 o = { f2bu(v.x), f2bu(v.y), f2bu(v.z), f2bu(v.w) };
    wcat[(size_t)j*768 + k4] = o;
}

// feats f32 [b][p][d] -> fbf bf16 [b*p][d], ftr bf16 [b][d][PP] (pad0), meanf f32 [b][d]
__global__ void k_tr2(const float* __restrict__ feats,
                      unsigned short* __restrict__ fbf,
                      unsigned short* __restrict__ ftr,
                      float* __restrict__ meanf){
    __shared__ unsigned short sm[64][260];
    __shared__ float4 msum[256];
    int dc = blockIdx.x;    // 0..7 (256-d chunk)
    int b  = blockIdx.y;    // 0..63
    int tid = threadIdx.x;
    int c4 = tid & 63;
    int rq = tid >> 6;
    int D0 = dc*256;
    float4 acc = {0.f,0.f,0.f,0.f};
    for (int pc = 0; pc < 4; pc++){
        __syncthreads();
        #pragma unroll
        for (int i = 0; i < 16; i++){
            int rl = rq + 4*i;
            int p = pc*64 + rl;
            float4 v = {0.f,0.f,0.f,0.f};
            if (p < NP) v = *(const float4*)(feats + ((size_t)(b*NP + p))*ND + D0 + c4*4);
            acc.x += v.x; acc.y += v.y; acc.z += v.z; acc.w += v.w;
            ushort4 u4 = { f2bu(v.x), f2bu(v.y), f2bu(v.z), f2bu(v.w) };
            if (p < NP) *(ushort4*)(fbf + ((size_t)(b*NP + p))*ND + D0 + c4*4) = u4;
            *(ushort4*)&sm[rl][c4*4] = u4;
        }
        __syncthreads();
        int gmax = (pc == 3) ? 1 : 8;
        for (int g = 0; g < gmax; g++){
            u16x8 o;
            #pragma unroll
            for (int k = 0; k < 8; k++) o[k] = sm[g*8 + k][tid];
            *(u16x8*)(ftr + ((size_t)(b*ND + D0 + tid))*PP + pc*64 + g*8) = o;
        }
    }
    msum[tid] = acc;
    __syncthreads();
    if (tid < 64){
        float4 s0 = msum[tid], s1 = msum[tid+64], s2 = msum[tid+128], s3 = msum[tid+192];
        float4 tot = { (s0.x+s1.x)+(s2.x+s3.x), (s0.y+s1.y)+(s2.y+s3.y),
                       (s0.z+s1.z)+(s2.z+s3.z), (s0.w+s1.w)+(s2.w+s3.w) };
        tot.x *= (1.f/196.f); tot.y *= (1.f/196.f); tot.z *= (1.f/196.f); tot.w *= (1.f/196.f);
        *(float4*)(meanf + (size_t)b*ND + D0 + tid*4) = tot;
    }
}

// h0 (->bf16 hbf + xh h-part) and c0 (->f32 cst)
__global__ void k_hc0(const float* __restrict__ meanf,
                      const float* __restrict__ hw, const float* __restrict__ hb,
                      const float* __restrict__ cw, const float* __restrict__ cb,
                      unsigned short* __restrict__ hbf, float* __restrict__ cst,
                      unsigned short* __restrict__ xh){
    int sel = blockIdx.y;
    const float* wmat = sel ? cw : hw;
    const float* bias = sel ? cb : hb;
    int jg = blockIdx.x;
    int tid = threadIdx.x;
    int b = tid & 63, jj = tid >> 6;
    int j = jg*4 + jj;
    __shared__ float ml[64][33];
    __shared__ float wl[4][32];
    float acc = 0.f;
    for (int kc = 0; kc < ND; kc += 32){
        __syncthreads();
        #pragma unroll
        for (int q = 0; q < 8; q++){
            int lin = tid + q*256;
            int r = lin >> 5, kk = lin & 31;
            ml[r][kk] = meanf[r*ND + kc + kk];
        }
        if (tid < 128){ int r = tid >> 5, kk = tid & 31; wl[r][kk] = wmat[(jg*4 + r)*ND + kc + kk]; }
        __syncthreads();
        #pragma unroll
        for (int kk = 0; kk < 32; kk++) acc += ml[b][kk] * wl[jj][kk];
    }
    acc += bias[j];
    if (sel) cst[b*NH + j] = acc;
    else { unsigned short u = f2bu(acc); hbf[b*NH + j] = u; xh[b*NKX + 2560 + j] = u; }
}

// ---------------- 128x128-tile GEMM core (m97 structure) ----------------
template<int K>
__device__ __forceinline__ void gemm128(const unsigned short* __restrict__ A,
                                        const unsigned short* __restrict__ B,
                                        int brow, int bcol, f32x4 acc[4][4]){
    __shared__ unsigned short As[128*32];
    __shared__ unsigned short Bs[128*32];
    int tid = threadIdx.x;
    int w = tid >> 6, l = tid & 63;
    int wr = (w >> 1) * 64, wc = (w & 1) * 64;
    int lr = l & 15, kg = (l >> 4) * 8;
    const unsigned short* ga0 = A + (size_t)(brow + (tid >> 2))*K + (tid & 3)*8;
    const unsigned short* gb0 = B + (size_t)(bcol + (tid >> 2))*K + (tid & 3)*8;
    for (int k0 = 0; k0 < K; k0 += 32){
        __syncthreads();
        gll16(ga0 + k0,                As + w*512);
        gll16(ga0 + (size_t)64*K + k0, As + 2048 + w*512);
        gll16(gb0 + k0,                Bs + w*512);
        gll16(gb0 + (size_t)64*K + k0, Bs + 2048 + w*512);
        __syncthreads();
        bf16x8 af[4], bfr[4];
        #pragma unroll
        for (int mi = 0; mi < 4; mi++)
            af[mi] = *(const bf16x8*)(As + (wr + mi*16 + lr)*32 + kg);
        #pragma unroll
        for (int ni = 0; ni < 4; ni++)
            bfr[ni] = *(const bf16x8*)(Bs + (wc + ni*16 + lr)*32 + kg);
        #pragma unroll
        for (int ni = 0; ni < 4; ni++){
            #pragma unroll
            for (int mi = 0; mi < 4; mi++)
                acc[mi][ni] = __builtin_amdgcn_mfma_f32_16x16x32_bf16(af[mi], bfr[ni], acc[mi][ni], 0, 0, 0);
        }
    }
}

__global__ void k_gemm_att1(const unsigned short* __restrict__ fbf,
                            const unsigned short* __restrict__ encw,
                            const float* __restrict__ enc_b,
                            unsigned short* __restrict__ att1){
    f32x4 acc[4][4] = {};
    int brow = blockIdx.x*128, bcol = blockIdx.y*128;
    gemm128<ND>(fbf, encw, brow, bcol, acc);
    int w = threadIdx.x >> 6, l = threadIdx.x & 63;
    int wr = (w >> 1) * 64, wc = (w & 1) * 64;
    int r0 = brow + wr + (l >> 4)*4;
    int c0 = bcol + wc + (l & 15);
    #pragma unroll
    for (int ni = 0; ni < 4; ni++){
        int col = c0 + ni*16;
        float eb = enc_b[col];
        #pragma unroll
        for (int mi = 0; mi < 4; mi++){
            #pragma unroll
            for (int r = 0; r < 4; r++)
                att1[(size_t)(r0 + mi*16 + r)*NA + col] = f2bu(acc[mi][ni][r] + eb);
        }
    }
}

__global__ void k_gemm_cls(const unsigned short* __restrict__ hsb,
                           const unsigned short* __restrict__ clsw,
                           const float* __restrict__ cls_b,
                           const int* __restrict__ lengths,
                           float* __restrict__ yout){
    f32x4 acc[4][4] = {};
    int brow = blockIdx.x*128, bcol = blockIdx.y*128;
    gemm128<NH>(hsb, clsw, brow, bcol, acc);
    int w = threadIdx.x >> 6, l = threadIdx.x & 63;
    int wr = (w >> 1) * 64, wc = (w & 1) * 64;
    int r0 = brow + wr + (l >> 4)*4;
    int c0 = bcol + wc + (l & 15);
    #pragma unroll
    for (int ni = 0; ni < 4; ni++){
        int col = c0 + ni*16;
        if (col >= NV) continue;
        float cb = cls_b[col];
        #pragma unroll
        for (int mi = 0; mi < 4; mi++){
            #pragma unroll
            for (int r = 0; r < 4; r++){
                int grow = r0 + mi*16 + r;
                if (grow >= NT*64) continue;
                int t = grow >> 6, bb = grow & 63;
                int active = t < (lengths[bb] - 1);
                yout[((size_t)bb*NT + t)*NV + col] = active ? (acc[mi][ni][r] + cb) : 0.f;
            }
        }
    }
}

// ---------------- loop phase bodies (shared by coop + discrete paths) ----------------

struct LoopArgs {
    const unsigned short* att1;
    const unsigned short* ftr;
    const unsigned short* hwb;
    const unsigned short* wcat;
    const float* emb;
    const int* captions;
    const int* lengths;
    const float* dec_b;
    const float* att_w;
    const float* att_b;
    const float* f_beta_b;
    const float* b_ih;
    const float* b_hh;
    unsigned short* hbf;
    unsigned short* hsb;
    unsigned short* xh;
    float* cst;
    float* hp;
    float* ews;
    float* part;
    float* alphas;
};

// vb < 128
__device__ __forceinline__ void phase_lstm(const LoopArgs& a, int vb, int tid, int t){
    int idx = vb*256 + tid;
    int b = idx >> 9, j = idx & 511;
    float gi = a.b_ih[j]        + a.b_hh[j];
    float gf = a.b_ih[512 + j]  + a.b_hh[512 + j];
    float gg = a.b_ih[1024 + j] + a.b_hh[1024 + j];
    float go = a.b_ih[1536 + j] + a.b_hh[1536 + j];
    #pragma unroll
    for (int s = 0; s < 8; s++){
        const float* pb = a.part + (size_t)(s*64 + b)*2048;
        gi += pb[j]; gf += pb[512 + j]; gg += pb[1024 + j]; go += pb[1536 + j];
    }
    float c = a.cst[b*NH + j];
    float c2 = sigm(gf)*c + sigm(gi)*tanhf(gg);
    float h2 = sigm(go)*tanhf(c2);
    a.cst[b*NH + j] = c2;
    unsigned short u = f2bu(h2);
    a.hbf[b*NH + j] = u;
    a.xh[b*NKX + 2560 + j] = u;
    a.hsb[((size_t)(t - 1)*64 + b)*NH + j] = u;
}

// vb < 160
__device__ __forceinline__ void phase_hproj(const LoopArgs& a, int vb, int tid){
    int w = tid >> 6, l = tid & 63;
    int row = 16*w + (l & 15);
    int col = vb*16 + (l & 15);
    int kg = (l >> 4) * 8;
    f32x4 acc = {};
    for (int k0 = 0; k0 < NH; k0 += 32){
        bf16x8 af = *(const bf16x8*)(a.hbf + row*NH + k0 + kg);
        bf16x8 bv = *(const bf16x8*)(a.hwb + (size_t)col*NH + k0 + kg);
        acc = __builtin_amdgcn_mfma_f32_16x16x32_bf16(af, bv, acc, 0, 0, 0);
    }
    int r0 = 16*w + (l >> 4)*4;
    #pragma unroll
    for (int r = 0; r < 4; r++)
        a.hp[(r0 + r)*2560 + col] = acc[r];
}

// vb < 256
__device__ __forceinline__ void phase_e(const LoopArgs& a, int vb, int tid, int t){
    __shared__ float at2[NA];
    __shared__ float aw[NA];
    int b = vb >> 2, pc = vb & 3;
    for (int j = tid; j < NA; j += 256){
        at2[j] = a.hp[b*2560 + j] + a.dec_b[j];
        aw[j]  = a.att_w[j];
    }
    if (pc == 0){
        int cap = a.captions[b*20 + t];
        for (int k = tid; k < NE; k += 256)
            a.xh[b*NKX + k] = f2bu(a.emb[(size_t)cap*NE + k]);
    }
    __syncthreads();
    int pl = tid >> 2, q = tid & 3;
    if (pl < 49){
        int p = pc*49 + pl;
        const unsigned short* arow = a.att1 + ((size_t)(b*NP + p))*NA + q*128;
        float s = 0.f;
        for (int a0 = 0; a0 < 128; a0 += 8){
            bf16x8 v = *(const bf16x8*)(arow + a0);
            #pragma unroll
            for (int e = 0; e < 8; e++){
                int ai = q*128 + a0 + e;
                float x = b2f(v[e]) + at2[ai];
                s += fmaxf(x, 0.f) * aw[ai];
            }
        }
        s += __shfl_xor(s, 1);
        s += __shfl_xor(s, 2);
        if (q == 0) a.ews[b*NP + p] = s + a.att_b[0];
    }
    __syncthreads();
}

// vb < 512
__device__ __forceinline__ void phase_awe(const LoopArgs& a, int vb, int tid, int t){
    __shared__ float al[PP];
    __shared__ float red[256];
    int dc = vb >> 6, b = vb & 63;
    float v = (tid < NP) ? a.ews[b*NP + tid] : -1e30f;
    red[tid] = v; __syncthreads();
    for (int s = 128; s > 0; s >>= 1){ if (tid < s) red[tid] = fmaxf(red[tid], red[tid+s]); __syncthreads(); }
    float m = red[0]; __syncthreads();
    float ev = (tid < NP) ? __expf(v - m) : 0.f;
    red[tid] = ev; __syncthreads();
    for (int s = 128; s > 0; s >>= 1){ if (tid < s) red[tid] += red[tid+s]; __syncthreads(); }
    float inv = 1.f / red[0];
    if (tid < NP) al[tid] = ev * inv;
    if (tid >= NP && tid < PP) al[tid] = 0.f;
    __syncthreads();
    if (dc == 0 && tid < NP){
        int active = t < (a.lengths[b] - 1);
        a.alphas[((size_t)b*NT + t)*NP + tid] = active ? al[tid] : 0.f;
    }
    int d = dc*256 + tid;
    const unsigned short* fr = a.ftr + ((size_t)(b*ND + d))*PP;
    float a0 = 0.f, a1 = 0.f, a2 = 0.f, a3 = 0.f;
    #pragma unroll
    for (int c = 0; c < 25; c++){
        bf16x8 vv = *(const bf16x8*)(fr + c*8);
        float s = 0.f;
        #pragma unroll
        for (int j = 0; j < 8; j++) s += al[c*8 + j] * b2f(vv[j]);
        if ((c & 3) == 0) a0 += s; else if ((c & 3) == 1) a1 += s;
        else if ((c & 3) == 2) a2 += s; else a3 += s;
    }
    float accv = (a0 + a1) + (a2 + a3);
    float g = sigm(a.hp[b*2560 + 512 + d] + a.f_beta_b[d]);
    a.xh[b*NKX + 512 + d] = f2bu(g * accv);
    __syncthreads();
}

// vb < 1024
__device__ __forceinline__ void phase_gates(const LoopArgs& a, int vb, int tid){
    int nt = vb & 127, s = vb >> 7;
    int w = tid >> 6, l = tid & 63;
    int row = 16*w + (l & 15);
    int col = nt*16 + (l & 15);
    int kg = (l >> 4) * 8;
    int kbase = s*384;
    f32x4 acc = {};
    for (int k0 = 0; k0 < 384; k0 += 32){
        bf16x8 af = *(const bf16x8*)(a.xh + row*NKX + kbase + k0 + kg);
        bf16x8 bv = *(const bf16x8*)(a.wcat + (size_t)col*NKX + kbase + k0 + kg);
        acc = __builtin_amdgcn_mfma_f32_16x16x32_bf16(af, bv, acc, 0, 0, 0);
    }
    int r0 = 16*w + (l >> 4)*4;
    #pragma unroll
    for (int r = 0; r < 4; r++)
        a.part[(size_t)(s*64 + r0 + r)*2048 + col] = acc[r];
}

// ---------------- cooperative persistent kernel (grid-stride, any nblk) ----------------

__global__ void __launch_bounds__(256, 2) k_loop(LoopArgs a, int nblk){
    cg::grid_group grid = cg::this_grid();
    const int bid = blockIdx.x;
    const int tid = threadIdx.x;
    for (int t = 0; t < NT; t++){
        if (t > 0) for (int vb = bid; vb < 128; vb += nblk) phase_lstm(a, vb, tid, t);
        __threadfence(); grid.sync();
        for (int vb = bid; vb < 160; vb += nblk) phase_hproj(a, vb, tid);
        __threadfence(); grid.sync();
        for (int vb = bid; vb < 256; vb += nblk) phase_e(a, vb, tid, t);
        __threadfence(); grid.sync();
        for (int vb = bid; vb < 512; vb += nblk) phase_awe(a, vb, tid, t);
        __threadfence(); grid.sync();
        for (int vb = bid; vb < 1024; vb += nblk) phase_gates(a, vb, tid);
        __threadfence(); grid.sync();
    }
    for (int vb = bid; vb < 128; vb += nblk) phase_lstm(a, vb, tid, NT);
}

// ---------------- discrete fallback wrappers (exact same bodies) ----------------

__global__ void k_lstm_w(LoopArgs a, int t){ phase_lstm(a, blockIdx.x, threadIdx.x, t); }
__global__ void k_hproj_w(LoopArgs a){ phase_hproj(a, blockIdx.x, threadIdx.x); }
__global__ void k_e_w(LoopArgs a, int t){ phase_e(a, blockIdx.x, threadIdx.x, t); }
__global__ void k_awe_w(LoopArgs a, int t){ phase_awe(a, blockIdx.x, threadIdx.x, t); }
__global__ void k_gates_w(LoopArgs a){ phase_gates(a, blockIdx.x, threadIdx.x); }

// ---------------- launch ----------------

extern "C" void kernel_launch(void* const* d_in, const int* in_sizes, int n_in,
                              void* d_out, int out_size, void* d_ws, size_t ws_size,
                              hipStream_t stream){
    const float* features = (const float*)d_in[0];
    const int*   captions = (const int*)d_in[1];
    const int*   lengths  = (const int*)d_in[2];
    const float* emb      = (const float*)d_in[3];
    const float* W_ih     = (const float*)d_in[4];
    const float* b_ih     = (const float*)d_in[5];
    const float* W_hh     = (const float*)d_in[6];
    const float* b_hh     = (const float*)d_in[7];
    const float* h_fc_w   = (const float*)d_in[8];
    const float* h_fc_b   = (const float*)d_in[9];
    const float* c_fc_w   = (const float*)d_in[10];
    const float* c_fc_b   = (const float*)d_in[11];
    const float* f_beta_w = (const float*)d_in[12];
    const float* f_beta_b = (const float*)d_in[13];
    const float* cls_w    = (const float*)d_in[14];
    const float* cls_b    = (const float*)d_in[15];
    const float* enc_w    = (const float*)d_in[16];
    const float* enc_b    = (const float*)d_in[17];
    const float* dec_w    = (const float*)d_in[18];
    const float* dec_b    = (const float*)d_in[19];
    const float* att_w    = (const float*)d_in[20];
    const float* att_b    = (const float*)d_in[21];

    char* w = (char*)d_ws;
    size_t off = 0;
    auto alloc = [&](size_t bytes)->char*{
        char* p = w + off;
        off += (bytes + 255) & ~(size_t)255;
        return p;
    };
    unsigned short* fbf   = (unsigned short*)alloc((size_t)NROW*ND*2);
    unsigned short* ftr   = (unsigned short*)alloc((size_t)NB*ND*PP*2);
    unsigned short* att1  = (unsigned short*)alloc((size_t)NROW*NA*2);
    unsigned short* encwb = (unsigned short*)alloc((size_t)NA*ND*2);
    unsigned short* hwb   = (unsigned short*)alloc((size_t)2560*NH*2);
    unsigned short* wcat  = (unsigned short*)alloc((size_t)2048*NKX*2);
    unsigned short* clswb = (unsigned short*)alloc((size_t)NVP*NH*2);
    unsigned short* hsb   = (unsigned short*)alloc((size_t)MROW*NH*2);
    unsigned short* hbf   = (unsigned short*)alloc((size_t)64*NH*2);
    unsigned short* xh    = (unsigned short*)alloc((size_t)64*NKX*2);
    float* meanf = (float*)alloc((size_t)64*ND*4);
    float* cst   = (float*)alloc((size_t)64*NH*4);
    float* hp    = (float*)alloc((size_t)64*2560*4);
    float* ews   = (float*)alloc((size_t)64*NP*4);
    float* part  = (float*)alloc((size_t)8*64*2048*4);

    float* yout = (float*)d_out;
    float* alphas_out = yout + (size_t)NB*NT*NV;

    // setup
    k_tr2<<<dim3(8, 64), 256, 0, stream>>>(features, fbf, ftr, meanf);
    k_cast4<<<1024, 256, 0, stream>>>((const float4*)enc_w, (ushort4*)encwb, NA*ND/4);
    k_cast4<<<256, 256, 0, stream>>>((const float4*)dec_w, (ushort4*)hwb, 512*512/4);
    k_cast4<<<1024, 256, 0, stream>>>((const float4*)f_beta_w, (ushort4*)(hwb + 512*512), 2048*512/4);
    k_wcat4<<<dim3(2048, 3), 256, 0, stream>>>((const float4*)W_ih, (const float4*)W_hh, (ushort4*)wcat);
    k_cast4<<<2048, 256, 0, stream>>>((const float4*)cls_w, (ushort4*)clswb, NV*NH/4);
    hipMemsetAsync(clswb + (size_t)NV*NH, 0, (size_t)(NVP - NV)*NH*2, stream);
    hipMemsetAsync(hsb + (size_t)NT*64*NH, 0, (size_t)(MROW - NT*64)*NH*2, stream);
    k_hc0<<<dim3(128, 2), 256, 0, stream>>>(meanf, h_fc_w, h_fc_b, c_fc_w, c_fc_b, hbf, cst, xh);
    k_gemm_att1<<<dim3(98, 4), 256, 0, stream>>>(fbf, encwb, enc_b, att1);

    LoopArgs la;
    la.att1 = att1; la.ftr = ftr; la.hwb = hwb; la.wcat = wcat;
    la.emb = emb; la.captions = captions; la.lengths = lengths;
    la.dec_b = dec_b; la.att_w = att_w; la.att_b = att_b; la.f_beta_b = f_beta_b;
    la.b_ih = b_ih; la.b_hh = b_hh;
    la.hbf = hbf; la.hsb = hsb; la.xh = xh;
    la.cst = cst; la.hp = hp; la.ews = ews; la.part = part; la.alphas = alphas_out;

    // decide coop vs fallback (deterministic queries only)
    int dev = 0; hipGetDevice(&dev);
    int coopOK = 0; hipDeviceGetAttribute(&coopOK, hipDeviceAttributeCooperativeLaunch, dev);
    int numCU = 0; hipDeviceGetAttribute(&numCU, hipDeviceAttributeMultiprocessorCount, dev);
    int maxBlkPerCU = 0;
    hipOccupancyMaxActiveBlocksPerMultiprocessor(&maxBlkPerCU, (const void*)k_loop, 256, 0);
    long capacity = (long)maxBlkPerCU * (numCU > 0 ? numCU : 0);
    int nblk = (int)(capacity < 512 ? capacity : 512);
    bool useCoop = (coopOK != 0) && (nblk >= 64);

    if (useCoop){
        int nb = nblk;
        void* kargs[] = { (void*)&la, (void*)&nb };
        hipError_t e = hipLaunchCooperativeKernel((const void*)k_loop, dim3(nblk), dim3(256),
                                                  kargs, 0, stream);
        if (e != hipSuccess) useCoop = false;
    }
    if (!useCoop){
        for (int t = 0; t < NT; t++){
            if (t > 0) k_lstm_w<<<128, 256, 0, stream>>>(la, t);
            k_hproj_w<<<160, 256, 0, stream>>>(la);
            k_e_w<<<256, 256, 0, stream>>>(la, t);
            k_awe_w<<<512, 256, 0, stream>>>(la, t);
            k_gates_w<<<1024, 256, 0, stream>>>(la);
        }
        k_lstm_w<<<128, 256, 0, stream>>>(la, NT);
    }

    k_gemm_cls<<<dim3(10, 79), 256, 0, stream>>>(hsb, clswb, cls_b, lengths, yout);
}

// Round 5
// 2081.679 us; speedup vs baseline: 2.8522x; 2.8522x over previous
//
#include <hip/hip_runtime.h>
#include <math.h>

typedef __attribute__((ext_vector_type(8))) short bf16x8;
typedef __attribute__((ext_vector_type(8))) unsigned short u16x8;
typedef __attribute__((ext_vector_type(4))) float f32x4;

#define NB 64
#define NP 196
#define ND 2048
#define NA 512
#define NH 512
#define NE 512
#define NV 10000
#define NT 19
#define NKX 3072
#define NROW (NB*NP)
#define NVP 10112          // padded vocab (79*128)
#define MROW 1280          // padded hsb rows (10*128)
#define PP 200             // padded p-dim for ftr

__device__ __forceinline__ unsigned short f2bu(float f){
    unsigned int u; __builtin_memcpy(&u, &f, 4);
    u = (u + 0x7FFFu + ((u >> 16) & 1u)) >> 16;
    return (unsigned short)u;
}
__device__ __forceinline__ float b2f(unsigned short s){
    unsigned int u = ((unsigned int)s) << 16;
    float f; __builtin_memcpy(&f, &u, 4); return f;
}
__device__ __forceinline__ float sigm(float x){ return 1.f/(1.f + __expf(-x)); }

__device__ __forceinline__ void gll16(const void* g, void* l){
    __builtin_amdgcn_global_load_lds(
        (const __attribute__((address_space(1))) void*)g,
        (__attribute__((address_space(3))) void*)l, 16, 0, 0);
}

// ---------------- setup kernels ----------------

// all weight casts + pads in one kernel (float4 -> ushort4)
__global__ void k_prep(const float4* __restrict__ enc_w, const float4* __restrict__ dec_w,
                       const float4* __restrict__ f_beta_w, const float4* __restrict__ W_ih,
                       const float4* __restrict__ W_hh, const float4* __restrict__ cls_w,
                       ushort4* __restrict__ encwb, ushort4* __restrict__ hwb,
                       ushort4* __restrict__ wcat, ushort4* __restrict__ clswb,
                       ushort4* __restrict__ hsb_pad){
    const int n0 = NA*ND/4;          // 262144
    const int n1 = 2560*512/4;       // 327680
    const int n2 = 2048*3072/4;      // 1572864
    const int n3 = NVP*NH/4;         // 1294336
    const int n4 = 64*512/4;         // 8192
    const int total = n0+n1+n2+n3+n4;
    int stride = gridDim.x*blockDim.x;
    for (int i = blockIdx.x*blockDim.x + threadIdx.x; i < total; i += stride){
        int idx = i;
        float4 v; ushort4 o;
        if (idx < n0){
            v = enc_w[idx];
            o = (ushort4){ f2bu(v.x), f2bu(v.y), f2bu(v.z), f2bu(v.w) };
            encwb[idx] = o; continue;
        }
        idx -= n0;
        if (idx < n1){
            v = (idx < 512*512/4) ? dec_w[idx] : f_beta_w[idx - 512*512/4];
            o = (ushort4){ f2bu(v.x), f2bu(v.y), f2bu(v.z), f2bu(v.w) };
            hwb[idx] = o; continue;
        }
        idx -= n1;
        if (idx < n2){
            int j = idx / 768, kk4 = idx - j*768;
            v = (kk4 < 640) ? W_ih[(size_t)j*640 + kk4] : W_hh[(size_t)j*128 + (kk4 - 640)];
            o = (ushort4){ f2bu(v.x), f2bu(v.y), f2bu(v.z), f2bu(v.w) };
            wcat[idx] = o; continue;
        }
        idx -= n2;
        if (idx < n3){
            if (idx < NV*NH/4){
                v = cls_w[idx];
                o = (ushort4){ f2bu(v.x), f2bu(v.y), f2bu(v.z), f2bu(v.w) };
            } else o = (ushort4){0,0,0,0};
            clswb[idx] = o; continue;
        }
        idx -= n3;
        hsb_pad[idx] = (ushort4){0,0,0,0};
    }
}

// feats f32 [b][p][d] -> fbf bf16 [b*p][d], ftr bf16 [b][d][PP] (pad0), meanf f32 [b][d]
__global__ void k_tr2(const float* __restrict__ feats,
                      unsigned short* __restrict__ fbf,
                      unsigned short* __restrict__ ftr,
                      float* __restrict__ meanf){
    __shared__ unsigned short sm[64][260];
    __shared__ float4 msum[256];
    int dc = blockIdx.x;    // 0..7 (256-d chunk)
    int b  = blockIdx.y;    // 0..63
    int tid = threadIdx.x;
    int c4 = tid & 63;
    int rq = tid >> 6;
    int D0 = dc*256;
    float4 acc = {0.f,0.f,0.f,0.f};
    for (int pc = 0; pc < 4; pc++){
        __syncthreads();
        #pragma unroll
        for (int i = 0; i < 16; i++){
            int rl = rq + 4*i;
            int p = pc*64 + rl;
            float4 v = {0.f,0.f,0.f,0.f};
            if (p < NP) v = *(const float4*)(feats + ((size_t)(b*NP + p))*ND + D0 + c4*4);
            acc.x += v.x; acc.y += v.y; acc.z += v.z; acc.w += v.w;
            ushort4 u4 = { f2bu(v.x), f2bu(v.y), f2bu(v.z), f2bu(v.w) };
            if (p < NP) *(ushort4*)(fbf + ((size_t)(b*NP + p))*ND + D0 + c4*4) = u4;
            *(ushort4*)&sm[rl][c4*4] = u4;
        }
        __syncthreads();
        int gmax = (pc == 3) ? 1 : 8;
        for (int g = 0; g < gmax; g++){
            u16x8 o;
            #pragma unroll
            for (int k = 0; k < 8; k++) o[k] = sm[g*8 + k][tid];
            *(u16x8*)(ftr + ((size_t)(b*ND + D0 + tid))*PP + pc*64 + g*8) = o;
        }
    }
    msum[tid] = acc;
    __syncthreads();
    if (tid < 64){
        float4 s0 = msum[tid], s1 = msum[tid+64], s2 = msum[tid+128], s3 = msum[tid+192];
        float4 tot = { (s0.x+s1.x)+(s2.x+s3.x), (s0.y+s1.y)+(s2.y+s3.y),
                       (s0.z+s1.z)+(s2.z+s3.z), (s0.w+s1.w)+(s2.w+s3.w) };
        tot.x *= (1.f/196.f); tot.y *= (1.f/196.f); tot.z *= (1.f/196.f); tot.w *= (1.f/196.f);
        *(float4*)(meanf + (size_t)b*ND + D0 + tid*4) = tot;
    }
}

// h0 (->bf16 hbf + xh h-part) and c0 (->f32 cst)
__global__ void k_hc0(const float* __restrict__ meanf,
                      const float* __restrict__ hw, const float* __restrict__ hb,
                      const float* __restrict__ cw, const float* __restrict__ cb,
                      unsigned short* __restrict__ hbf, float* __restrict__ cst,
                      unsigned short* __restrict__ xh){
    int sel = blockIdx.y;
    const float* wmat = sel ? cw : hw;
    const float* bias = sel ? cb : hb;
    int jg = blockIdx.x;
    int tid = threadIdx.x;
    int b = tid & 63, jj = tid >> 6;
    int j = jg*4 + jj;
    __shared__ float ml[64][33];
    __shared__ float wl[4][32];
    float acc = 0.f;
    for (int kc = 0; kc < ND; kc += 32){
        __syncthreads();
        #pragma unroll
        for (int q = 0; q < 8; q++){
            int lin = tid + q*256;
            int r = lin >> 5, kk = lin & 31;
            ml[r][kk] = meanf[r*ND + kc + kk];
        }
        if (tid < 128){ int r = tid >> 5, kk = tid & 31; wl[r][kk] = wmat[(jg*4 + r)*ND + kc + kk]; }
        __syncthreads();
        #pragma unroll
        for (int kk = 0; kk < 32; kk++) acc += ml[b][kk] * wl[jj][kk];
    }
    acc += bias[j];
    if (sel) cst[b*NH + j] = acc;
    else { unsigned short u = f2bu(acc); hbf[b*NH + j] = u; xh[b*NKX + 2560 + j] = u; }
}

// ---------------- 128x128-tile GEMM core (m97 structure, verified) ----------------
template<int K>
__device__ __forceinline__ void gemm128(const unsigned short* __restrict__ A,
                                        const unsigned short* __restrict__ B,
                                        int brow, int bcol, f32x4 acc[4][4]){
    __shared__ unsigned short As[128*32];
    __shared__ unsigned short Bs[128*32];
    int tid = threadIdx.x;
    int w = tid >> 6, l = tid & 63;
    int wr = (w >> 1) * 64, wc = (w & 1) * 64;
    int lr = l & 15, kg = (l >> 4) * 8;
    const unsigned short* ga0 = A + (size_t)(brow + (tid >> 2))*K + (tid & 3)*8;
    const unsigned short* gb0 = B + (size_t)(bcol + (tid >> 2))*K + (tid & 3)*8;
    for (int k0 = 0; k0 < K; k0 += 32){
        __syncthreads();
        gll16(ga0 + k0,                As + w*512);
        gll16(ga0 + (size_t)64*K + k0, As + 2048 + w*512);
        gll16(gb0 + k0,                Bs + w*512);
        gll16(gb0 + (size_t)64*K + k0, Bs + 2048 + w*512);
        __syncthreads();
        bf16x8 af[4], bfr[4];
        #pragma unroll
        for (int mi = 0; mi < 4; mi++)
            af[mi] = *(const bf16x8*)(As + (wr + mi*16 + lr)*32 + kg);
        #pragma unroll
        for (int ni = 0; ni < 4; ni++)
            bfr[ni] = *(const bf16x8*)(Bs + (wc + ni*16 + lr)*32 + kg);
        #pragma unroll
        for (int ni = 0; ni < 4; ni++){
            #pragma unroll
            for (int mi = 0; mi < 4; mi++)
                acc[mi][ni] = __builtin_amdgcn_mfma_f32_16x16x32_bf16(af[mi], bfr[ni], acc[mi][ni], 0, 0, 0);
        }
    }
}

__global__ void k_gemm_att1(const unsigned short* __restrict__ fbf,
                            const unsigned short* __restrict__ encw,
                            const float* __restrict__ enc_b,
                            unsigned short* __restrict__ att1){
    f32x4 acc[4][4] = {};
    int brow = blockIdx.x*128, bcol = blockIdx.y*128;
    gemm128<ND>(fbf, encw, brow, bcol, acc);
    int w = threadIdx.x >> 6, l = threadIdx.x & 63;
    int wr = (w >> 1) * 64, wc = (w & 1) * 64;
    int r0 = brow + wr + (l >> 4)*4;
    int c0 = bcol + wc + (l & 15);
    #pragma unroll
    for (int ni = 0; ni < 4; ni++){
        int col = c0 + ni*16;
        float eb = enc_b[col];
        #pragma unroll
        for (int mi = 0; mi < 4; mi++){
            #pragma unroll
            for (int r = 0; r < 4; r++)
                att1[(size_t)(r0 + mi*16 + r)*NA + col] = f2bu(acc[mi][ni][r] + eb);
        }
    }
}

__global__ void k_gemm_cls(const unsigned short* __restrict__ hsb,
                           const unsigned short* __restrict__ clsw,
                           const float* __restrict__ cls_b,
                           const int* __restrict__ lengths,
                           float* __restrict__ yout){
    f32x4 acc[4][4] = {};
    int brow = blockIdx.x*128, bcol = blockIdx.y*128;
    gemm128<NH>(hsb, clsw, brow, bcol, acc);
    int w = threadIdx.x >> 6, l = threadIdx.x & 63;
    int wr = (w >> 1) * 64, wc = (w & 1) * 64;
    int r0 = brow + wr + (l >> 4)*4;
    int c0 = bcol + wc + (l & 15);
    #pragma unroll
    for (int ni = 0; ni < 4; ni++){
        int col = c0 + ni*16;
        if (col >= NV) continue;
        float cb = cls_b[col];
        #pragma unroll
        for (int mi = 0; mi < 4; mi++){
            #pragma unroll
            for (int r = 0; r < 4; r++){
                int grow = r0 + mi*16 + r;
                if (grow >= NT*64) continue;
                int t = grow >> 6, bb = grow & 63;
                int active = t < (lengths[bb] - 1);
                yout[((size_t)bb*NT + t)*NV + col] = active ? (acc[mi][ni][r] + cb) : 0.f;
            }
        }
    }
}

// ---------------- per-step kernels (3 dispatches/step) ----------------

// D1: per-b block: lstm + at2(h@dec_w^T) + e-scores + softmax; writes alphas, alw,
//     xh emb/h parts, hbf, hsb, cst.
__global__ void k_step1(const float* __restrict__ part,
                        const float* __restrict__ b_ih, const float* __restrict__ b_hh,
                        float* __restrict__ cst, unsigned short* __restrict__ hbf,
                        unsigned short* __restrict__ hsb, unsigned short* __restrict__ xh,
                        const unsigned short* __restrict__ hwb,      // rows 0..511 = dec_w
                        const float* __restrict__ dec_b,
                        const unsigned short* __restrict__ att1,
                        const float* __restrict__ att_w, const float* __restrict__ att_b,
                        const float* __restrict__ emb, const int* __restrict__ captions,
                        const int* __restrict__ lengths,
                        float* __restrict__ alw, float* __restrict__ alphas, int t){
    __shared__ float hls[512];
    __shared__ float at2s[512];
    __shared__ float aws[512];
    __shared__ float red[256];
    int b = blockIdx.x, tid = threadIdx.x;
    if (t > 0){
        for (int j = tid; j < 512; j += 256){
            float gi = b_ih[j]        + b_hh[j];
            float gf = b_ih[512 + j]  + b_hh[512 + j];
            float gg = b_ih[1024 + j] + b_hh[1024 + j];
            float go = b_ih[1536 + j] + b_hh[1536 + j];
            #pragma unroll
            for (int s = 0; s < 8; s++){
                const float* pb = part + (size_t)(s*64 + b)*2048;
                gi += pb[j]; gf += pb[512 + j]; gg += pb[1024 + j]; go += pb[1536 + j];
            }
            float c = cst[b*NH + j];
            float c2 = sigm(gf)*c + sigm(gi)*tanhf(gg);
            float h2 = sigm(go)*tanhf(c2);
            cst[b*NH + j] = c2;
            hls[j] = h2;
            unsigned short u = f2bu(h2);
            hbf[b*NH + j] = u;
            xh[b*NKX + 2560 + j] = u;
            hsb[((size_t)(t - 1)*64 + b)*NH + j] = u;
        }
    } else {
        for (int j = tid; j < 512; j += 256) hls[j] = b2f(hbf[b*NH + j]);
    }
    int cap = captions[b*20 + t];
    for (int k = tid; k < 512; k += 256){
        xh[b*NKX + k] = f2bu(emb[(size_t)cap*NE + k]);
        aws[k] = att_w[k];
    }
    __syncthreads();
    // at2: 2 outputs per thread
    {
        float acc0 = dec_b[tid], acc1 = dec_b[tid + 256];
        const unsigned short* w0 = hwb + (size_t)tid*512;
        const unsigned short* w1 = hwb + (size_t)(tid + 256)*512;
        for (int j = 0; j < 512; j += 8){
            bf16x8 x0 = *(const bf16x8*)(w0 + j);
            bf16x8 x1 = *(const bf16x8*)(w1 + j);
            #pragma unroll
            for (int e = 0; e < 8; e++){
                float hv = hls[j + e];
                acc0 += hv * b2f((unsigned short)x0[e]);
                acc1 += hv * b2f((unsigned short)x1[e]);
            }
        }
        at2s[tid] = acc0; at2s[tid + 256] = acc1;
    }
    __syncthreads();
    // scores: one p per thread (196 active)
    float s = -1e30f;
    if (tid < NP){
        const unsigned short* arow = att1 + ((size_t)(b*NP + tid))*NA;
        float acc = att_b[0];
        for (int a0 = 0; a0 < 512; a0 += 8){
            bf16x8 v = *(const bf16x8*)(arow + a0);
            #pragma unroll
            for (int e = 0; e < 8; e++){
                float x = b2f((unsigned short)v[e]) + at2s[a0 + e];
                acc += fmaxf(x, 0.f) * aws[a0 + e];
            }
        }
        s = acc;
    }
    red[tid] = s; __syncthreads();
    for (int st = 128; st > 0; st >>= 1){ if (tid < st) red[tid] = fmaxf(red[tid], red[tid+st]); __syncthreads(); }
    float m = red[0]; __syncthreads();
    float ev = (tid < NP) ? __expf(s - m) : 0.f;
    red[tid] = ev; __syncthreads();
    for (int st = 128; st > 0; st >>= 1){ if (tid < st) red[tid] += red[tid+st]; __syncthreads(); }
    float inv = 1.f / red[0];
    float al = ev * inv;
    if (tid < PP) alw[b*PP + tid] = (tid < NP) ? al : 0.f;
    if (tid < NP){
        int active = t < (lengths[b] - 1);
        alphas[((size_t)b*NT + t)*NP + tid] = active ? al : 0.f;
    }
}

// D2: blocks 0..127: hbeta = hbf@f_beta_w^T + f_beta_b (MFMA, f32 out)
//     blocks 128..639: awe_raw[b][d] = sum_p alw[b][p]*ftr[b][d][p]
__global__ void k_step2(const unsigned short* __restrict__ hbf,
                        const unsigned short* __restrict__ hwb,      // rows 512.. = f_beta_w
                        const float* __restrict__ f_beta_b,
                        const float* __restrict__ alw,
                        const unsigned short* __restrict__ ftr,
                        float* __restrict__ hbeta, float* __restrict__ awer){
    int tid = threadIdx.x;
    if (blockIdx.x < 128){
        int nt = blockIdx.x;
        int w = tid >> 6, l = tid & 63;
        int row = 16*w + (l & 15);
        int col = nt*16 + (l & 15);
        int kg = (l >> 4) * 8;
        f32x4 acc = {};
        for (int k0 = 0; k0 < NH; k0 += 32){
            bf16x8 af = *(const bf16x8*)(hbf + row*NH + k0 + kg);
            bf16x8 bv = *(const bf16x8*)(hwb + (size_t)(512 + col)*NH + k0 + kg);
            acc = __builtin_amdgcn_mfma_f32_16x16x32_bf16(af, bv, acc, 0, 0, 0);
        }
        int r0 = 16*w + (l >> 4)*4;
        float fb = f_beta_b[col];
        #pragma unroll
        for (int r = 0; r < 4; r++)
            hbeta[(size_t)(r0 + r)*2048 + col] = acc[r] + fb;
    } else {
        __shared__ float als[PP];
        int id2 = blockIdx.x - 128;
        int b = id2 >> 3, dc = id2 & 7;
        if (tid < PP) als[tid] = alw[b*PP + tid];
        __syncthreads();
        int d = dc*256 + tid;
        const unsigned short* fr = ftr + ((size_t)(b*ND + d))*PP;
        float a0 = 0.f, a1 = 0.f, a2 = 0.f, a3 = 0.f;
        #pragma unroll
        for (int c = 0; c < 25; c++){
            bf16x8 vv = *(const bf16x8*)(fr + c*8);
            float ss = 0.f;
            #pragma unroll
            for (int j = 0; j < 8; j++) ss += als[c*8 + j] * b2f((unsigned short)vv[j]);
            if ((c & 3) == 0) a0 += ss; else if ((c & 3) == 1) a1 += ss;
            else if ((c & 3) == 2) a2 += ss; else a3 += ss;
        }
        awer[(size_t)b*2048 + d] = (a0 + a1) + (a2 + a3);
    }
}

// D3: gates GEMM with on-the-fly A assembly (emb | sigm(hbeta)*awe_raw | h)
//     grid (16 n-tiles, 8 k-slices); out part[s][64][2048]
#define AST 392
__global__ void k_gates2(const unsigned short* __restrict__ xh,
                         const float* __restrict__ hbeta, const float* __restrict__ awer,
                         const unsigned short* __restrict__ wcat,
                         float* __restrict__ part){
    __shared__ unsigned short As[64*AST];
    __shared__ unsigned short Bs[128*32];
    int nt = blockIdx.x;    // 0..15
    int s  = blockIdx.y;    // 0..7
    int tid = threadIdx.x;
    int w = tid >> 6, l = tid & 63;
    // A assembly: rows 0..63 (=b), cols kk 0..383 (K-slice s)
    #pragma unroll 4
    for (int rr = 0; rr < 16; rr++){
        int r = (tid >> 6) + rr*4;
        #pragma unroll
        for (int c = 0; c < 6; c++){
            int kk = c*64 + (tid & 63);
            int k = s*384 + kk;
            unsigned short v;
            if (k < 512 || k >= 2560) v = xh[r*NKX + k];
            else {
                int d = k - 512;
                float g = sigm(hbeta[(size_t)r*2048 + d]);
                v = f2bu(g * awer[(size_t)r*2048 + d]);
            }
            As[r*AST + kk] = v;
        }
    }
    // MFMA: out 64 rows x 128 cols; 4 waves: wave w -> cols [w*32, w*32+32)
    int wc = w*32;
    int lr = l & 15, kg = (l >> 4) * 8;
    const unsigned short* gb0 = wcat + (size_t)(nt*128 + (tid >> 2))*NKX + s*384 + (tid & 3)*8;
    f32x4 acc[4][2] = {};
    for (int k0 = 0; k0 < 384; k0 += 32){
        __syncthreads();
        gll16(gb0 + k0,                 Bs + w*512);
        gll16(gb0 + (size_t)64*NKX + k0, Bs + 2048 + w*512);
        __syncthreads();
        bf16x8 af[4], bfr[2];
        #pragma unroll
        for (int mi = 0; mi < 4; mi++)
            af[mi] = *(const bf16x8*)(As + (mi*16 + lr)*AST + k0 + kg);
        #pragma unroll
        for (int ni = 0; ni < 2; ni++)
            bfr[ni] = *(const bf16x8*)(Bs + (wc + ni*16 + lr)*32 + kg);
        #pragma unroll
        for (int ni = 0; ni < 2; ni++){
            #pragma unroll
            for (int mi = 0; mi < 4; mi++)
                acc[mi][ni] = __builtin_amdgcn_mfma_f32_16x16x32_bf16(af[mi], bfr[ni], acc[mi][ni], 0, 0, 0);
        }
    }
    int r0 = (l >> 4)*4;
    #pragma unroll
    for (int ni = 0; ni < 2; ni++){
        int col = nt*128 + wc + ni*16 + (l & 15);
        #pragma unroll
        for (int mi = 0; mi < 4; mi++){
            #pragma unroll
            for (int r = 0; r < 4; r++)
                part[(size_t)(s*64 + mi*16 + r0 + r)*2048 + col] = acc[mi][ni][r];
        }
    }
}

// final LSTM (t = NT) -> hsb[18]
__global__ void k_lstm_fin(const float* __restrict__ part,
                           const float* __restrict__ b_ih, const float* __restrict__ b_hh,
                           float* __restrict__ cst, unsigned short* __restrict__ hsb){
    int idx = blockIdx.x*256 + threadIdx.x;
    int b = idx >> 9, j = idx & 511;
    float gi = b_ih[j]        + b_hh[j];
    float gf = b_ih[512 + j]  + b_hh[512 + j];
    float gg = b_ih[1024 + j] + b_hh[1024 + j];
    float go = b_ih[1536 + j] + b_hh[1536 + j];
    #pragma unroll
    for (int s = 0; s < 8; s++){
        const float* pb = part + (size_t)(s*64 + b)*2048;
        gi += pb[j]; gf += pb[512 + j]; gg += pb[1024 + j]; go += pb[1536 + j];
    }
    float c = cst[b*NH + j];
    float c2 = sigm(gf)*c + sigm(gi)*tanhf(gg);
    float h2 = sigm(go)*tanhf(c2);
    hsb[((size_t)(NT - 1)*64 + b)*NH + j] = f2bu(h2);
}

// ---------------- launch ----------------

extern "C" void kernel_launch(void* const* d_in, const int* in_sizes, int n_in,
                              void* d_out, int out_size, void* d_ws, size_t ws_size,
                              hipStream_t stream){
    const float* features = (const float*)d_in[0];
    const int*   captions = (const int*)d_in[1];
    const int*   lengths  = (const int*)d_in[2];
    const float* emb      = (const float*)d_in[3];
    const float* W_ih     = (const float*)d_in[4];
    const float* b_ih     = (const float*)d_in[5];
    const float* W_hh     = (const float*)d_in[6];
    const float* b_hh     = (const float*)d_in[7];
    const float* h_fc_w   = (const float*)d_in[8];
    const float* h_fc_b   = (const float*)d_in[9];
    const float* c_fc_w   = (const float*)d_in[10];
    const float* c_fc_b   = (const float*)d_in[11];
    const float* f_beta_w = (const float*)d_in[12];
    const float* f_beta_b = (const float*)d_in[13];
    const float* cls_w    = (const float*)d_in[14];
    const float* cls_b    = (const float*)d_in[15];
    const float* enc_w    = (const float*)d_in[16];
    const float* enc_b    = (const float*)d_in[17];
    const float* dec_w    = (const float*)d_in[18];
    const float* dec_b    = (const float*)d_in[19];
    const float* att_w    = (const float*)d_in[20];
    const float* att_b    = (const float*)d_in[21];

    char* w = (char*)d_ws;
    size_t off = 0;
    auto alloc = [&](size_t bytes)->char*{
        char* p = w + off;
        off += (bytes + 255) & ~(size_t)255;
        return p;
    };
    unsigned short* fbf   = (unsigned short*)alloc((size_t)NROW*ND*2);
    unsigned short* ftr   = (unsigned short*)alloc((size_t)NB*ND*PP*2);
    unsigned short* att1  = (unsigned short*)alloc((size_t)NROW*NA*2);
    unsigned short* encwb = (unsigned short*)alloc((size_t)NA*ND*2);
    unsigned short* hwb   = (unsigned short*)alloc((size_t)2560*NH*2);
    unsigned short* wcat  = (unsigned short*)alloc((size_t)2048*NKX*2);
    unsigned short* clswb = (unsigned short*)alloc((size_t)NVP*NH*2);
    unsigned short* hsb   = (unsigned short*)alloc((size_t)MROW*NH*2);
    unsigned short* hbf   = (unsigned short*)alloc((size_t)64*NH*2);
    unsigned short* xh    = (unsigned short*)alloc((size_t)64*NKX*2);
    float* meanf = (float*)alloc((size_t)64*ND*4);
    float* cst   = (float*)alloc((size_t)64*NH*4);
    float* hbeta = (float*)alloc((size_t)64*2048*4);
    float* alw   = (float*)alloc((size_t)64*PP*4);
    float* awer  = (float*)alloc((size_t)64*2048*4);
    float* part  = (float*)alloc((size_t)8*64*2048*4);

    float* yout = (float*)d_out;
    float* alphas_out = yout + (size_t)NB*NT*NV;

    // setup (4 dispatches)
    k_tr2<<<dim3(8, 64), 256, 0, stream>>>(features, fbf, ftr, meanf);
    k_prep<<<1024, 256, 0, stream>>>((const float4*)enc_w, (const float4*)dec_w,
                                     (const float4*)f_beta_w, (const float4*)W_ih,
                                     (const float4*)W_hh, (const float4*)cls_w,
                                     (ushort4*)encwb, (ushort4*)hwb, (ushort4*)wcat,
                                     (ushort4*)clswb, (ushort4*)(hsb + (size_t)NT*64*NH));
    k_hc0<<<dim3(128, 2), 256, 0, stream>>>(meanf, h_fc_w, h_fc_b, c_fc_w, c_fc_b, hbf, cst, xh);
    k_gemm_att1<<<dim3(98, 4), 256, 0, stream>>>(fbf, encwb, enc_b, att1);

    // 19 steps x 3 dispatches
    for (int t = 0; t < NT; t++){
        k_step1<<<64, 256, 0, stream>>>(part, b_ih, b_hh, cst, hbf, hsb, xh,
                                        hwb, dec_b, att1, att_w, att_b,
                                        emb, captions, lengths, alw, alphas_out, t);
        k_step2<<<640, 256, 0, stream>>>(hbf, hwb, f_beta_b, alw, ftr, hbeta, awer);
        k_gates2<<<dim3(16, 8), 256, 0, stream>>>(xh, hbeta, awer, wcat, part);
    }
    k_lstm_fin<<<128, 256, 0, stream>>>(part, b_ih, b_hh, cst, hsb);
    k_gemm_cls<<<dim3(10, 79), 256, 0, stream>>>(hsb, clswb, cls_b, lengths, yout);
}

// Round 7
// 1125.063 us; speedup vs baseline: 5.2774x; 1.8503x over previous
//
#include <hip/hip_runtime.h>
#include <math.h>

typedef __attribute__((ext_vector_type(8))) short bf16x8;
typedef __attribute__((ext_vector_type(8))) unsigned short u16x8;
typedef __attribute__((ext_vector_type(4))) float f32x4;

#define NB 64
#define NP 196
#define ND 2048
#define NA 512
#define NH 512
#define NE 512
#define NV 10000
#define NT 19
#define NROW (NB*NP)
#define NVP 10112          // padded vocab (79*128)
#define MROW 1280          // padded rows (10*128) for hsb/embcat
#define PP 200             // padded p-dim for ftr

__device__ __forceinline__ unsigned short f2bu(float f){
    unsigned int u; __builtin_memcpy(&u, &f, 4);
    u = (u + 0x7FFFu + ((u >> 16) & 1u)) >> 16;
    return (unsigned short)u;
}
__device__ __forceinline__ float b2f(unsigned short s){
    unsigned int u = ((unsigned int)s) << 16;
    float f; __builtin_memcpy(&f, &u, 4); return f;
}
__device__ __forceinline__ float sigm(float x){ return 1.f/(1.f + __expf(-x)); }

__device__ __forceinline__ void gll16(const void* g, void* l){
    __builtin_amdgcn_global_load_lds(
        (const __attribute__((address_space(1))) void*)g,
        (__attribute__((address_space(3))) void*)l, 16, 0, 0);
}

// ---------------- setup kernels ----------------

// one kernel for all weight repacks/casts (float4 -> ushort4)
__global__ void k_prep(const float4* __restrict__ enc_w, const float4* __restrict__ dec_w,
                       const float4* __restrict__ f_beta_w, const float4* __restrict__ W_ih,
                       const float4* __restrict__ W_hh, const float4* __restrict__ h_fc_w,
                       const float4* __restrict__ c_fc_w, const float4* __restrict__ cls_w,
                       ushort4* __restrict__ encwb, ushort4* __restrict__ whp,
                       ushort4* __restrict__ wgates, ushort4* __restrict__ wembb,
                       ushort4* __restrict__ whc, ushort4* __restrict__ clswb,
                       ushort4* __restrict__ hsb_pad){
    const int n0 = NA*ND/4;          // encwb   262144
    const int n1 = 2560*512/4;       // whp     327680
    const int n2 = 2048*2560/4;      // wgates  1310720
    const int n3 = 2048*512/4;       // wembb   262144
    const int n4 = 1024*2048/4;      // whc     524288
    const int n5 = NVP*NH/4;         // clswb   1294336
    const int n6 = 64*512/4;         // hsb pad 8192
    const int total = n0+n1+n2+n3+n4+n5+n6;
    int stride = gridDim.x*blockDim.x;
    for (int i = blockIdx.x*blockDim.x + threadIdx.x; i < total; i += stride){
        int idx = i;
        float4 v; ushort4 o;
        if (idx < n0){
            v = enc_w[idx];
            o.x = f2bu(v.x); o.y = f2bu(v.y); o.z = f2bu(v.z); o.w = f2bu(v.w);
            encwb[idx] = o; continue;
        }
        idx -= n0;
        if (idx < n1){
            v = (idx < 512*512/4) ? dec_w[idx] : f_beta_w[idx - 512*512/4];
            o.x = f2bu(v.x); o.y = f2bu(v.y); o.z = f2bu(v.z); o.w = f2bu(v.w);
            whp[idx] = o; continue;
        }
        idx -= n1;
        if (idx < n2){
            int j = idx / 640, kk4 = idx - j*640;
            v = (kk4 < 512) ? W_ih[(size_t)j*640 + 128 + kk4] : W_hh[(size_t)j*128 + (kk4 - 512)];
            o.x = f2bu(v.x); o.y = f2bu(v.y); o.z = f2bu(v.z); o.w = f2bu(v.w);
            wgates[idx] = o; continue;
        }
        idx -= n2;
        if (idx < n3){
            int j = idx >> 7, kk4 = idx & 127;
            v = W_ih[(size_t)j*640 + kk4];
            o.x = f2bu(v.x); o.y = f2bu(v.y); o.z = f2bu(v.z); o.w = f2bu(v.w);
            wembb[idx] = o; continue;
        }
        idx -= n3;
        if (idx < n4){
            v = (idx < 512*2048/4) ? h_fc_w[idx] : c_fc_w[idx - 512*2048/4];
            o.x = f2bu(v.x); o.y = f2bu(v.y); o.z = f2bu(v.z); o.w = f2bu(v.w);
            whc[idx] = o; continue;
        }
        idx -= n4;
        if (idx < n5){
            if (idx < NV*NH/4){
                v = cls_w[idx];
                o.x = f2bu(v.x); o.y = f2bu(v.y); o.z = f2bu(v.z); o.w = f2bu(v.w);
            } else { o.x = 0; o.y = 0; o.z = 0; o.w = 0; }
            clswb[idx] = o; continue;
        }
        idx -= n5;
        o.x = 0; o.y = 0; o.z = 0; o.w = 0;
        hsb_pad[idx] = o;
    }
}

// feats f32 [b][p][d] -> fbf bf16, ftr bf16 [b][d][PP] (pad0), partial sums mp[ph][b][d]
__global__ void k_tr3(const float* __restrict__ feats,
                      unsigned short* __restrict__ fbf,
                      unsigned short* __restrict__ ftr,
                      float* __restrict__ mp){
    __shared__ unsigned short sm[64][260];
    __shared__ float4 msum[256];
    int dc = blockIdx.x;    // 0..7 (256-d chunk)
    int b  = blockIdx.y;    // 0..63
    int ph = blockIdx.z;    // 0..1 (p-half)
    int tid = threadIdx.x;
    int c4 = tid & 63;
    int rq = tid >> 6;
    int D0 = dc*256;
    float4 acc = {0.f,0.f,0.f,0.f};
    for (int pcl = 0; pcl < 2; pcl++){
        int pc = ph*2 + pcl;
        __syncthreads();
        #pragma unroll
        for (int i = 0; i < 16; i++){
            int rl = rq + 4*i;
            int p = pc*64 + rl;
            float4 v = {0.f,0.f,0.f,0.f};
            if (p < NP) v = *(const float4*)(feats + ((size_t)(b*NP + p))*ND + D0 + c4*4);
            acc.x += v.x; acc.y += v.y; acc.z += v.z; acc.w += v.w;
            ushort4 u4;
            u4.x = f2bu(v.x); u4.y = f2bu(v.y); u4.z = f2bu(v.z); u4.w = f2bu(v.w);
            if (p < NP) *(ushort4*)(fbf + ((size_t)(b*NP + p))*ND + D0 + c4*4) = u4;
            *(ushort4*)&sm[rl][c4*4] = u4;
        }
        __syncthreads();
        int gmax = (pc == 3) ? 1 : 8;
        for (int g = 0; g < gmax; g++){
            u16x8 o;
            #pragma unroll
            for (int k = 0; k < 8; k++) o[k] = sm[g*8 + k][tid];
            *(u16x8*)(ftr + ((size_t)(b*ND + D0 + tid))*PP + pc*64 + g*8) = o;
        }
    }
    msum[tid] = acc;
    __syncthreads();
    if (tid < 64){
        float4 s0 = msum[tid], s1 = msum[tid+64], s2 = msum[tid+128], s3 = msum[tid+192];
        float4 tot = { (s0.x+s1.x)+(s2.x+s3.x), (s0.y+s1.y)+(s2.y+s3.y),
                       (s0.z+s1.z)+(s2.z+s3.z), (s0.w+s1.w)+(s2.w+s3.w) };
        *(float4*)(mp + ((size_t)ph*64 + b)*ND + D0 + tid*4) = tot;
    }
}

// meanbf[b][d] = bf16((mp0+mp1)/196)
__global__ void k_mean2(const float* __restrict__ mp, unsigned short* __restrict__ meanbf){
    int i = blockIdx.x*1024 + threadIdx.x*4;
    float4 a = *(const float4*)(mp + i);
    float4 b = *(const float4*)(mp + 64*ND + i);
    ushort4 o;
    o.x = f2bu((a.x+b.x)*(1.f/196.f)); o.y = f2bu((a.y+b.y)*(1.f/196.f));
    o.z = f2bu((a.z+b.z)*(1.f/196.f)); o.w = f2bu((a.w+b.w)*(1.f/196.f));
    *(ushort4*)(meanbf + i) = o;
}

// embcat[r][k] bf16 = emb[captions[b][t]][k], r = t*64+b (pad rows 0)
__global__ void k_embg(const float* __restrict__ emb, const int* __restrict__ captions,
                       unsigned short* __restrict__ embcat){
    int blk = blockIdx.x, tid = threadIdx.x;
    int r = blk*4 + (tid >> 6);
    int cg = tid & 63;
    u16x8 o;
    #pragma unroll
    for (int k = 0; k < 8; k++) o[k] = 0;
    if (r < NT*64){
        int t = r >> 6, b = r & 63;
        int tok = captions[b*20 + t];
        const float* e = emb + (size_t)tok*NE + cg*8;
        float4 v0 = *(const float4*)e;
        float4 v1 = *(const float4*)(e + 4);
        o[0] = f2bu(v0.x); o[1] = f2bu(v0.y); o[2] = f2bu(v0.z); o[3] = f2bu(v0.w);
        o[4] = f2bu(v1.x); o[5] = f2bu(v1.y); o[6] = f2bu(v1.z); o[7] = f2bu(v1.w);
    }
    *(u16x8*)(embcat + (size_t)r*NE + cg*8) = o;
}

// h0/c0 via MFMA: [h0|c0] = meanbf @ whc^T ; h0->hbf bf16, c0->cst f32
__global__ void k_hc0m(const unsigned short* __restrict__ meanbf,
                       const unsigned short* __restrict__ whc,
                       const float* __restrict__ h_fc_b, const float* __restrict__ c_fc_b,
                       unsigned short* __restrict__ hbf, float* __restrict__ cst){
    int tid = threadIdx.x;
    int w = tid >> 6, l = tid & 63;
    int nt = blockIdx.x;               // 0..63
    int row = 16*w + (l & 15);
    int col = nt*16 + (l & 15);
    int kg = (l >> 4) * 8;
    f32x4 acc = {};
    for (int k0 = 0; k0 < ND; k0 += 32){
        bf16x8 af = *(const bf16x8*)(meanbf + (size_t)row*ND + k0 + kg);
        bf16x8 bv = *(const bf16x8*)(whc + (size_t)col*ND + k0 + kg);
        acc = __builtin_amdgcn_mfma_f32_16x16x32_bf16(af, bv, acc, 0, 0, 0);
    }
    int r0 = 16*w + (l >> 4)*4;
    #pragma unroll
    for (int r = 0; r < 4; r++){
        int b = r0 + r;
        if (col < 512) hbf[b*NH + col] = f2bu(acc[r] + h_fc_b[col]);
        else           cst[b*NH + (col - 512)] = acc[r] + c_fc_b[col - 512];
    }
}

// ---------------- 128x128-tile GEMM core (m97 structure, verified) ----------------
template<int K>
__device__ __forceinline__ void gemm128(const unsigned short* __restrict__ A,
                                        const unsigned short* __restrict__ B,
                                        int brow, int bcol, f32x4 acc[4][4]){
    __shared__ unsigned short As[128*32];
    __shared__ unsigned short Bs[128*32];
    int tid = threadIdx.x;
    int w = tid >> 6, l = tid & 63;
    int wr = (w >> 1) * 64, wc = (w & 1) * 64;
    int lr = l & 15, kg = (l >> 4) * 8;
    const unsigned short* ga0 = A + (size_t)(brow + (tid >> 2))*K + (tid & 3)*8;
    const unsigned short* gb0 = B + (size_t)(bcol + (tid >> 2))*K + (tid & 3)*8;
    for (int k0 = 0; k0 < K; k0 += 32){
        __syncthreads();
        gll16(ga0 + k0,                As + w*512);
        gll16(ga0 + (size_t)64*K + k0, As + 2048 + w*512);
        gll16(gb0 + k0,                Bs + w*512);
        gll16(gb0 + (size_t)64*K + k0, Bs + 2048 + w*512);
        __syncthreads();
        bf16x8 af[4], bfr[4];
        #pragma unroll
        for (int mi = 0; mi < 4; mi++)
            af[mi] = *(const bf16x8*)(As + (wr + mi*16 + lr)*32 + kg);
        #pragma unroll
        for (int ni = 0; ni < 4; ni++)
            bfr[ni] = *(const bf16x8*)(Bs + (wc + ni*16 + lr)*32 + kg);
        #pragma unroll
        for (int ni = 0; ni < 4; ni++){
            #pragma unroll
            for (int mi = 0; mi < 4; mi++)
                acc[mi][ni] = __builtin_amdgcn_mfma_f32_16x16x32_bf16(af[mi], bfr[ni], acc[mi][ni], 0, 0, 0);
        }
    }
}

__global__ void k_gemm_att1(const unsigned short* __restrict__ fbf,
                            const unsigned short* __restrict__ encw,
                            const float* __restrict__ enc_b,
                            unsigned short* __restrict__ att1){
    f32x4 acc[4][4] = {};
    int brow = blockIdx.x*128, bcol = blockIdx.y*128;
    gemm128<ND>(fbf, encw, brow, bcol, acc);
    int w = threadIdx.x >> 6, l = threadIdx.x & 63;
    int wr = (w >> 1) * 64, wc = (w & 1) * 64;
    int r0 = brow + wr + (l >> 4)*4;
    int c0 = bcol + wc + (l & 15);
    #pragma unroll
    for (int ni = 0; ni < 4; ni++){
        int col = c0 + ni*16;
        float eb = enc_b[col];
        #pragma unroll
        for (int mi = 0; mi < 4; mi++){
            #pragma unroll
            for (int r = 0; r < 4; r++)
                att1[(size_t)(r0 + mi*16 + r)*NA + col] = f2bu(acc[mi][ni][r] + eb);
        }
    }
}

// gemb = embcat @ wembb^T + b_ih + b_hh  (f32, rows t*64+b)
__global__ void k_gemb(const unsigned short* __restrict__ embcat,
                       const unsigned short* __restrict__ wembb,
                       const float* __restrict__ b_ih, const float* __restrict__ b_hh,
                       float* __restrict__ gemb){
    f32x4 acc[4][4] = {};
    int brow = blockIdx.x*128, bcol = blockIdx.y*128;
    gemm128<NE>(embcat, wembb, brow, bcol, acc);
    int w = threadIdx.x >> 6, l = threadIdx.x & 63;
    int wr = (w >> 1) * 64, wc = (w & 1) * 64;
    int r0 = brow + wr + (l >> 4)*4;
    int c0 = bcol + wc + (l & 15);
    #pragma unroll
    for (int ni = 0; ni < 4; ni++){
        int col = c0 + ni*16;
        float bias = b_ih[col] + b_hh[col];
        #pragma unroll
        for (int mi = 0; mi < 4; mi++){
            #pragma unroll
            for (int r = 0; r < 4; r++)
                gemb[(size_t)(r0 + mi*16 + r)*2048 + col] = acc[mi][ni][r] + bias;
        }
    }
}

__global__ void k_gemm_cls(const unsigned short* __restrict__ hsb,
                           const unsigned short* __restrict__ clsw,
                           const float* __restrict__ cls_b,
                           const int* __restrict__ lengths,
                           float* __restrict__ yout){
    f32x4 acc[4][4] = {};
    int brow = blockIdx.x*128, bcol = blockIdx.y*128;
    gemm128<NH>(hsb, clsw, brow, bcol, acc);
    int w = threadIdx.x >> 6, l = threadIdx.x & 63;
    int wr = (w >> 1) * 64, wc = (w & 1) * 64;
    int r0 = brow + wr + (l >> 4)*4;
    int c0 = bcol + wc + (l & 15);
    #pragma unroll
    for (int ni = 0; ni < 4; ni++){
        int col = c0 + ni*16;
        if (col >= NV) continue;
        float cb = cls_b[col];
        #pragma unroll
        for (int mi = 0; mi < 4; mi++){
            #pragma unroll
            for (int r = 0; r < 4; r++){
                int grow = r0 + mi*16 + r;
                if (grow >= NT*64) continue;
                int t = grow >> 6, bb = grow & 63;
                int active = t < (lengths[bb] - 1);
                yout[((size_t)bb*NT + t)*NV + col] = active ? (acc[mi][ni][r] + cb) : 0.f;
            }
        }
    }
}

// ---------------- per-step kernels ----------------

// D1: lstm finalize for step t-1 (t in 1..19): gates = gemb[t-1] + sum part[0..9]
__global__ void k_lstm(const float* __restrict__ part, const float* __restrict__ gemb,
                       float* __restrict__ cst, unsigned short* __restrict__ hbf,
                       unsigned short* __restrict__ hsb, int t){
    int idx = blockIdx.x*256 + threadIdx.x;
    int b = idx >> 9, j = idx & 511;
    const float* ge = gemb + ((size_t)(t - 1)*64 + b)*2048;
    float gi = ge[j], gf = ge[512 + j], gg = ge[1024 + j], go = ge[1536 + j];
    #pragma unroll
    for (int s = 0; s < 10; s++){
        const float* pb = part + (size_t)(s*64 + b)*2048;
        gi += pb[j]; gf += pb[512 + j]; gg += pb[1024 + j]; go += pb[1536 + j];
    }
    float c = cst[b*NH + j];
    float c2 = sigm(gf)*c + sigm(gi)*tanhf(gg);
    float h2 = sigm(go)*tanhf(c2);
    cst[b*NH + j] = c2;
    unsigned short u = f2bu(h2);
    hbf[b*NH + j] = u;
    hsb[((size_t)(t - 1)*64 + b)*NH + j] = u;
}

// D2: hp[b][col] = h@[dec_w|f_beta_w]^T + bias  (N=2560, biases folded)
__global__ void k_hproj(const unsigned short* __restrict__ hbf,
                        const unsigned short* __restrict__ whp,
                        const float* __restrict__ dec_b, const float* __restrict__ f_beta_b,
                        float* __restrict__ hp){
    int w = threadIdx.x >> 6, l = threadIdx.x & 63;
    int nt = blockIdx.x;                   // 0..159
    int row = 16*w + (l & 15);
    int col = nt*16 + (l & 15);
    int kg = (l >> 4) * 8;
    f32x4 acc = {};
    for (int k0 = 0; k0 < NH; k0 += 32){
        bf16x8 af = *(const bf16x8*)(hbf + row*NH + k0 + kg);
        bf16x8 bv = *(const bf16x8*)(whp + (size_t)col*NH + k0 + kg);
        acc = __builtin_amdgcn_mfma_f32_16x16x32_bf16(af, bv, acc, 0, 0, 0);
    }
    int r0 = 16*w + (l >> 4)*4;
    float bias = (col < 512) ? dec_b[col] : f_beta_b[col - 512];
    #pragma unroll
    for (int r = 0; r < 4; r++)
        hp[(r0 + r)*2560 + col] = acc[r] + bias;
}

// D3: e scores
__global__ void k_e(const unsigned short* __restrict__ att1,
                    const float* __restrict__ hp,
                    const float* __restrict__ att_w, const float* __restrict__ att_b,
                    float* __restrict__ ews){
    __shared__ float at2[NA];
    __shared__ float aw[NA];
    int b = blockIdx.x >> 2, pc = blockIdx.x & 3;
    int tid = threadIdx.x;
    for (int j = tid; j < NA; j += 256){
        at2[j] = hp[b*2560 + j];
        aw[j]  = att_w[j];
    }
    __syncthreads();
    int pl = tid >> 2, q = tid & 3;
    if (pl < 49){
        int p = pc*49 + pl;
        const unsigned short* arow = att1 + ((size_t)(b*NP + p))*NA + q*128;
        float s = 0.f;
        for (int a0 = 0; a0 < 128; a0 += 8){
            bf16x8 v = *(const bf16x8*)(arow + a0);
            #pragma unroll
            for (int e = 0; e < 8; e++){
                int ai = q*128 + a0 + e;
                float x = b2f((unsigned short)v[e]) + at2[ai];
                s += fmaxf(x, 0.f) * aw[ai];
            }
        }
        s += __shfl_xor(s, 1);
        s += __shfl_xor(s, 2);
        if (q == 0) ews[b*NP + p] = s + att_b[0];
    }
}

// D4: softmax + awe + gate -> xg bf16; alphas (dc==0)
__global__ void k_awe(const float* __restrict__ ews, const unsigned short* __restrict__ ftr,
                      const float* __restrict__ hp, const int* __restrict__ lengths,
                      unsigned short* __restrict__ xg, float* __restrict__ alphas, int t){
    __shared__ float al[PP];
    __shared__ float red[256];
    int dc = blockIdx.x;   // 0..7
    int b  = blockIdx.y;   // 0..63
    int tid = threadIdx.x;
    float v = (tid < NP) ? ews[b*NP + tid] : -1e30f;
    red[tid] = v; __syncthreads();
    for (int s = 128; s > 0; s >>= 1){ if (tid < s) red[tid] = fmaxf(red[tid], red[tid+s]); __syncthreads(); }
    float m = red[0]; __syncthreads();
    float ev = (tid < NP) ? __expf(v - m) : 0.f;
    red[tid] = ev; __syncthreads();
    for (int s = 128; s > 0; s >>= 1){ if (tid < s) red[tid] += red[tid+s]; __syncthreads(); }
    float inv = 1.f / red[0];
    if (tid < NP) al[tid] = ev * inv;
    if (tid >= NP && tid < PP) al[tid] = 0.f;
    __syncthreads();
    if (dc == 0 && tid < NP){
        int active = t < (lengths[b] - 1);
        alphas[((size_t)b*NT + t)*NP + tid] = active ? al[tid] : 0.f;
    }
    int d = dc*256 + tid;
    const unsigned short* fr = ftr + ((size_t)(b*ND + d))*PP;
    float a0 = 0.f, a1 = 0.f, a2 = 0.f, a3 = 0.f;
    #pragma unroll
    for (int c = 0; c < 25; c++){
        bf16x8 vv = *(const bf16x8*)(fr + c*8);
        float ss = 0.f;
        #pragma unroll
        for (int j = 0; j < 8; j++) ss += al[c*8 + j] * b2f((unsigned short)vv[j]);
        if ((c & 3) == 0) a0 += ss; else if ((c & 3) == 1) a1 += ss;
        else if ((c & 3) == 2) a2 += ss; else a3 += ss;
    }
    float accv = (a0 + a1) + (a2 + a3);
    float g = sigm(hp[b*2560 + 512 + d]);
    xg[b*2048 + d] = f2bu(g * accv);
}

// D5: gates split-K: s<8 -> xg @ W_ih-mid, s>=8 -> hbf @ W_hh  (K=256 each)
__global__ void k_gates(const unsigned short* __restrict__ xg,
                        const unsigned short* __restrict__ hbf,
                        const unsigned short* __restrict__ wgates,
                        float* __restrict__ part){
    int nt = blockIdx.x;   // 0..127
    int s  = blockIdx.y;   // 0..9
    int w = threadIdx.x >> 6, l = threadIdx.x & 63;
    int row = 16*w + (l & 15);
    int col = nt*16 + (l & 15);
    int kg = (l >> 4) * 8;
    const unsigned short* arow = (s < 8) ? (xg + row*2048 + s*256)
                                         : (hbf + row*512 + (s - 8)*256);
    const unsigned short* brow = wgates + (size_t)col*2560 + s*256;
    f32x4 acc = {};
    for (int k0 = 0; k0 < 256; k0 += 32){
        bf16x8 af = *(const bf16x8*)(arow + k0 + kg);
        bf16x8 bv = *(const bf16x8*)(brow + k0 + kg);
        acc = __builtin_amdgcn_mfma_f32_16x16x32_bf16(af, bv, acc, 0, 0, 0);
    }
    int r0 = 16*w + (l >> 4)*4;
    #pragma unroll
    for (int r = 0; r < 4; r++)
        part[(size_t)(s*64 + r0 + r)*2048 + col] = acc[r];
}

// final LSTM (t=19) -> hsb[18]
__global__ void k_lstm_fin(const float* __restrict__ part, const float* __restrict__ gemb,
                           const float* __restrict__ cst, unsigned short* __restrict__ hsb){
    int idx = blockIdx.x*256 + threadIdx.x;
    int b = idx >> 9, j = idx & 511;
    const float* ge = gemb + ((size_t)(NT - 1)*64 + b)*2048;
    float gi = ge[j], gf = ge[512 + j], gg = ge[1024 + j], go = ge[1536 + j];
    #pragma unroll
    for (int s = 0; s < 10; s++){
        const float* pb = part + (size_t)(s*64 + b)*2048;
        gi += pb[j]; gf += pb[512 + j]; gg += pb[1024 + j]; go += pb[1536 + j];
    }
    float c = cst[b*NH + j];
    float c2 = sigm(gf)*c + sigm(gi)*tanhf(gg);
    float h2 = sigm(go)*tanhf(c2);
    hsb[((size_t)(NT - 1)*64 + b)*NH + j] = f2bu(h2);
}

// ---------------- launch ----------------

extern "C" void kernel_launch(void* const* d_in, const int* in_sizes, int n_in,
                              void* d_out, int out_size, void* d_ws, size_t ws_size,
                              hipStream_t stream){
    const float* features = (const float*)d_in[0];
    const int*   captions = (const int*)d_in[1];
    const int*   lengths  = (const int*)d_in[2];
    const float* emb      = (const float*)d_in[3];
    const float* W_ih     = (const float*)d_in[4];
    const float* b_ih     = (const float*)d_in[5];
    const float* W_hh     = (const float*)d_in[6];
    const float* b_hh     = (const float*)d_in[7];
    const float* h_fc_w   = (const float*)d_in[8];
    const float* h_fc_b   = (const float*)d_in[9];
    const float* c_fc_w   = (const float*)d_in[10];
    const float* c_fc_b   = (const float*)d_in[11];
    const float* f_beta_w = (const float*)d_in[12];
    const float* f_beta_b = (const float*)d_in[13];
    const float* cls_w    = (const float*)d_in[14];
    const float* cls_b    = (const float*)d_in[15];
    const float* enc_w    = (const float*)d_in[16];
    const float* enc_b    = (const float*)d_in[17];
    const float* dec_w    = (const float*)d_in[18];
    const float* dec_b    = (const float*)d_in[19];
    const float* att_w    = (const float*)d_in[20];
    const float* att_b    = (const float*)d_in[21];

    char* w = (char*)d_ws;
    size_t off = 0;
    auto alloc = [&](size_t bytes)->char*{
        char* p = w + off;
        off += (bytes + 255) & ~(size_t)255;
        return p;
    };
    unsigned short* fbf    = (unsigned short*)alloc((size_t)NROW*ND*2);
    unsigned short* ftr    = (unsigned short*)alloc((size_t)NB*ND*PP*2);
    unsigned short* att1   = (unsigned short*)alloc((size_t)NROW*NA*2);
    unsigned short* encwb  = (unsigned short*)alloc((size_t)NA*ND*2);
    unsigned short* whp    = (unsigned short*)alloc((size_t)2560*NH*2);
    unsigned short* wgates = (unsigned short*)alloc((size_t)2048*2560*2);
    unsigned short* wembb  = (unsigned short*)alloc((size_t)2048*NE*2);
    unsigned short* whc    = (unsigned short*)alloc((size_t)1024*ND*2);
    unsigned short* clswb  = (unsigned short*)alloc((size_t)NVP*NH*2);
    unsigned short* embcat = (unsigned short*)alloc((size_t)MROW*NE*2);
    unsigned short* hsb    = (unsigned short*)alloc((size_t)MROW*NH*2);
    unsigned short* hbf    = (unsigned short*)alloc((size_t)64*NH*2);
    unsigned short* xg     = (unsigned short*)alloc((size_t)64*2048*2);
    unsigned short* meanbf = (unsigned short*)alloc((size_t)64*ND*2);
    float* mp    = (float*)alloc((size_t)2*64*ND*4);
    float* gemb  = (float*)alloc((size_t)MROW*2048*4);
    float* cst   = (float*)alloc((size_t)64*NH*4);
    float* hp    = (float*)alloc((size_t)64*2560*4);
    float* ews   = (float*)alloc((size_t)64*NP*4);
    float* part  = (float*)alloc((size_t)10*64*2048*4);

    float* yout = (float*)d_out;
    float* alphas_out = yout + (size_t)NB*NT*NV;

    // setup
    k_tr3<<<dim3(8, 64, 2), 256, 0, stream>>>(features, fbf, ftr, mp);
    k_prep<<<2048, 256, 0, stream>>>((const float4*)enc_w, (const float4*)dec_w,
                                     (const float4*)f_beta_w, (const float4*)W_ih,
                                     (const float4*)W_hh, (const float4*)h_fc_w,
                                     (const float4*)c_fc_w, (const float4*)cls_w,
                                     (ushort4*)encwb, (ushort4*)whp, (ushort4*)wgates,
                                     (ushort4*)wembb, (ushort4*)whc, (ushort4*)clswb,
                                     (ushort4*)(hsb + (size_t)NT*64*NH));
    k_embg<<<320, 256, 0, stream>>>(emb, captions, embcat);
    k_mean2<<<128, 256, 0, stream>>>(mp, meanbf);
    k_hc0m<<<64, 256, 0, stream>>>(meanbf, whc, h_fc_b, c_fc_b, hbf, cst);
    k_gemm_att1<<<dim3(98, 4), 256, 0, stream>>>(fbf, encwb, enc_b, att1);
    k_gemb<<<dim3(10, 16), 256, 0, stream>>>(embcat, wembb, b_ih, b_hh, gemb);

    // 19 steps
    for (int t = 0; t < NT; t++){
        if (t > 0)
            k_lstm<<<128, 256, 0, stream>>>(part, gemb, cst, hbf, hsb, t);
        k_hproj<<<160, 256, 0, stream>>>(hbf, whp, dec_b, f_beta_b, hp);
        k_e<<<256, 256, 0, stream>>>(att1, hp, att_w, att_b, ews);
        k_awe<<<dim3(8, 64), 256, 0, stream>>>(ews, ftr, hp, lengths, xg, alphas_out, t);
        k_gates<<<dim3(128, 10), 256, 0, stream>>>(xg, hbf, wgates, part);
    }
    k_lstm_fin<<<128, 256, 0, stream>>>(part, gemb, cst, hsb);
    k_gemm_cls<<<dim3(10, 79), 256, 0, stream>>>(hsb, clswb, cls_b, lengths, yout);
}